// Round 1
// baseline (77280.225 us; speedup 1.0000x reference)
//
#include <hip/hip_runtime.h>

// ---- problem constants ----
constexpr int SQ = 8192;   // sequence length
constexpr int HD = 256;    // hidden size H
constexpr int NG = 1024;   // 4H (gate width)

typedef __fp16 h2 __attribute__((ext_vector_type(2)));
typedef unsigned int uint;

__device__ __forceinline__ float sigm_f(float x) {
  float e = __builtin_amdgcn_exp2f(-1.4426950408889634f * x);
  return __builtin_amdgcn_rcpf(1.0f + e);
}
__device__ __forceinline__ float tanh_f(float x) {
  // tanh(x) = 1 - 2/(exp2(2x*log2e)+1); saturates correctly at +/-inf
  float e = __builtin_amdgcn_exp2f(2.885390081777927f * x);
  return 1.0f - 2.0f * __builtin_amdgcn_rcpf(1.0f + e);
}

// =====================================================================
// xp GEMM: out[d][m][n] = sum_k A[m][k] * W[d][k][n] + bias[d][n]
// A: [SQ][K] f32, W: [2][K][NG] f32, out: [2][SQ][NG] f32
// grid: (SQ/64, 32) ; 64x64 tile, 256 threads, 4x4 per thread, f32 FMA
// =====================================================================
__global__ __launch_bounds__(256) void gemm_xp(const float* __restrict__ A, int K,
                                               const float* __restrict__ W,
                                               const float* __restrict__ bias,
                                               float* __restrict__ out) {
  __shared__ float Al[16][64];  // [k][m] (transposed on load)
  __shared__ float Bl[16][64];  // [k][n]
  const int tid = threadIdx.x;
  const int bm = blockIdx.x * 64;
  const int d  = blockIdx.y >> 4;
  const int bn = (blockIdx.y & 15) * 64;
  const float* Wd = W + (size_t)d * K * NG;
  const float* bd = bias + (size_t)d * NG;
  float* outd = out + (size_t)d * SQ * NG;

  const int m4 = (tid >> 4) << 2;      // 0..60
  const int n4 = (tid & 15) << 2;      // 0..60
  const int am = tid >> 2, ak = (tid & 3) << 2;   // A loader: 64 m x 16 k
  const int bk = tid >> 4, bnn = (tid & 15) << 2; // B loader: 16 k x 64 n

  float acc[4][4] = {};
  for (int kt = 0; kt < K; kt += 16) {
    float4 av = *(const float4*)(A + (size_t)(bm + am) * K + kt + ak);
    float4 bv = *(const float4*)(Wd + (size_t)(kt + bk) * NG + bn + bnn);
    __syncthreads();
    Al[ak + 0][am] = av.x;
    Al[ak + 1][am] = av.y;
    Al[ak + 2][am] = av.z;
    Al[ak + 3][am] = av.w;
    *(float4*)&Bl[bk][bnn] = bv;
    __syncthreads();
#pragma unroll
    for (int k = 0; k < 16; ++k) {
      float4 a = *(const float4*)&Al[k][m4];
      float4 b = *(const float4*)&Bl[k][n4];
      float ar[4] = {a.x, a.y, a.z, a.w};
      float br[4] = {b.x, b.y, b.z, b.w};
#pragma unroll
      for (int i = 0; i < 4; ++i)
#pragma unroll
        for (int jj = 0; jj < 4; ++jj)
          acc[i][jj] = fmaf(ar[i], br[jj], acc[i][jj]);
    }
  }
#pragma unroll
  for (int i = 0; i < 4; ++i) {
    float4 o;
    o.x = acc[i][0] + bd[bn + n4 + 0];
    o.y = acc[i][1] + bd[bn + n4 + 1];
    o.z = acc[i][2] + bd[bn + n4 + 2];
    o.w = acc[i][3] + bd[bn + n4 + 3];
    *(float4*)(outd + (size_t)(bm + m4 + i) * NG + bn + n4) = o;
  }
}

// =====================================================================
// LSTM recurrence, one workgroup per direction (blockIdx.x = d).
// 1024 threads; thread j owns gate column j (q = j>>8 in {i,f,g,o}, u = j&255).
// W_hh column j: rows 0..183 as f16x2 in 92 VGPRs, rows 184..255 in LDS (144KB).
// h kept f16x2-packed in LDS (128 dwords), read as b128 broadcasts.
// xp: [2][SQ][NG] f32 (bias already folded in). obuf: [SQ][512] f32.
// =====================================================================
__global__ __launch_bounds__(1024, 4) void lstm_rec(const float* __restrict__ Whh,
                                                    const float* __restrict__ xp,
                                                    float* __restrict__ obuf) {
  __shared__ uint4 wlds[9 * 1024];  // 144KB: quad q8 = rows 184+8*q8.. for col j
  __shared__ float glds[1024];      // gate exchange
  __shared__ uint4 hlds[32];        // 128 dwords: dword r = h[2r],h[2r+1] f16-packed
  const int d = blockIdx.x;
  const int j = threadIdx.x;
  const float* W = Whh + (size_t)d * HD * NG;   // [256][1024]
  const float* xpd = xp + (size_t)d * SQ * NG;

  // ---- one-time weight load: column j ----
  h2 wreg[92];
#pragma unroll
  for (int r = 0; r < 92; ++r)
    wreg[r] = __builtin_amdgcn_cvt_pkrtz(W[(size_t)(2 * r) * NG + j],
                                         W[(size_t)(2 * r + 1) * NG + j]);
#pragma unroll
  for (int q8 = 0; q8 < 9; ++q8) {
    const int base = 184 + 8 * q8;
    uint4 v;
    v.x = __builtin_bit_cast(uint, __builtin_amdgcn_cvt_pkrtz(W[(size_t)(base + 0) * NG + j], W[(size_t)(base + 1) * NG + j]));
    v.y = __builtin_bit_cast(uint, __builtin_amdgcn_cvt_pkrtz(W[(size_t)(base + 2) * NG + j], W[(size_t)(base + 3) * NG + j]));
    v.z = __builtin_bit_cast(uint, __builtin_amdgcn_cvt_pkrtz(W[(size_t)(base + 4) * NG + j], W[(size_t)(base + 5) * NG + j]));
    v.w = __builtin_bit_cast(uint, __builtin_amdgcn_cvt_pkrtz(W[(size_t)(base + 6) * NG + j], W[(size_t)(base + 7) * NG + j]));
    wlds[q8 * 1024 + j] = v;
  }
  if (j < 32) hlds[j] = make_uint4(0u, 0u, 0u, 0u);
  __syncthreads();

  const int fwd = (d == 0) ? 1 : 0;
  int t = fwd ? 0 : SQ - 1;
  const int dt = fwd ? 1 : -1;
  const int qg = j >> 8;
  const int u = j & 255;
  float c = 0.0f;
  float xp_cur = xpd[(size_t)t * NG + j];

  for (int step = 0; step < SQ; ++step) {
    // prefetch next step's xp so HBM/L2 latency hides under the dots
    float xp_next = (step + 1 < SQ) ? xpd[(size_t)(t + dt) * NG + j] : 0.0f;

    float a0 = xp_cur, a1 = 0.0f;
#pragma unroll
    for (int cq = 0; cq < 23; ++cq) {        // rows 0..183 (register weights)
      uint4 hq = hlds[cq];                   // b128 broadcast
      a0 = __builtin_amdgcn_fdot2(wreg[4 * cq + 0], __builtin_bit_cast(h2, hq.x), a0, false);
      a1 = __builtin_amdgcn_fdot2(wreg[4 * cq + 1], __builtin_bit_cast(h2, hq.y), a1, false);
      a0 = __builtin_amdgcn_fdot2(wreg[4 * cq + 2], __builtin_bit_cast(h2, hq.z), a0, false);
      a1 = __builtin_amdgcn_fdot2(wreg[4 * cq + 3], __builtin_bit_cast(h2, hq.w), a1, false);
    }
#pragma unroll
    for (int q8 = 0; q8 < 9; ++q8) {         // rows 184..255 (LDS weights)
      uint4 wq = wlds[q8 * 1024 + j];
      uint4 hq = hlds[23 + q8];
      a0 = __builtin_amdgcn_fdot2(__builtin_bit_cast(h2, wq.x), __builtin_bit_cast(h2, hq.x), a0, false);
      a1 = __builtin_amdgcn_fdot2(__builtin_bit_cast(h2, wq.y), __builtin_bit_cast(h2, hq.y), a1, false);
      a0 = __builtin_amdgcn_fdot2(__builtin_bit_cast(h2, wq.z), __builtin_bit_cast(h2, hq.z), a0, false);
      a1 = __builtin_amdgcn_fdot2(__builtin_bit_cast(h2, wq.w), __builtin_bit_cast(h2, hq.w), a1, false);
    }
    float acc = a0 + a1;

    // activation (wave-uniform branch: q constant per wave)
    float act = (qg == 2) ? tanh_f(acc) : sigm_f(acc);
    glds[j] = act;
    __syncthreads();

    if (qg == 0) {   // waves 0-3: per-unit state update
      float iv = glds[u];
      float fv = glds[256 + u];
      float gv = glds[512 + u];
      float ov = glds[768 + u];
      c = fv * c + iv * gv;
      float hv = ov * tanh_f(c);
      obuf[(size_t)t * 512 + (d << 8) + u] = hv;
      float hn = __shfl_down(hv, 1);
      if (!(u & 1)) {
        h2 p = __builtin_amdgcn_cvt_pkrtz(hv, hn);
        ((uint*)hlds)[u >> 1] = __builtin_bit_cast(uint, p);
      }
    }
    __syncthreads();
    xp_cur = xp_next;
    t += dt;
  }
}

// =====================================================================
// classifier head: feat = [buf[S-1][0:256], buf[0][256:512]];
// out = (feat@w1 + b1)@w2 + b2
// =====================================================================
__global__ void cls_k(const float* __restrict__ buf, const float* __restrict__ w1,
                      const float* __restrict__ b1, const float* __restrict__ w2,
                      const float* __restrict__ b2, float* __restrict__ out) {
  __shared__ float feat[512];
  __shared__ float hid[32];
  const int t = threadIdx.x;
  feat[t] = (t < 256) ? buf[(size_t)(SQ - 1) * 512 + t] : buf[t];
  __syncthreads();
  if (t < 32) {
    float a = b1[t];
    for (int k = 0; k < 512; ++k) a = fmaf(feat[k], w1[k * 32 + t], a);
    hid[t] = a;
  }
  __syncthreads();
  if (t < 2) {
    float a = b2[t];
    for (int k = 0; k < 32; ++k) a = fmaf(hid[k], w2[k * 2 + t], a);
    out[t] = a;
  }
}

// =====================================================================
extern "C" void kernel_launch(void* const* d_in, const int* in_sizes, int n_in,
                              void* d_out, int out_size, void* d_ws, size_t ws_size,
                              hipStream_t stream) {
  const float* x     = (const float*)d_in[0];   // [8192,1024]
  const float* w_ih0 = (const float*)d_in[1];   // [2,1024,1024]
  const float* w_hh0 = (const float*)d_in[2];   // [2,256,1024]
  const float* b0    = (const float*)d_in[3];   // [2,1024]
  const float* w_ih  = (const float*)d_in[4];   // [4,2,512,1024]
  const float* w_hh  = (const float*)d_in[5];   // [4,2,256,1024]
  const float* b     = (const float*)d_in[6];   // [4,2,1024]
  const float* w1    = (const float*)d_in[7];   // [512,32]
  const float* b1    = (const float*)d_in[8];   // [32]
  const float* w2    = (const float*)d_in[9];   // [32,2]
  const float* b2    = (const float*)d_in[10];  // [2]

  float* xp   = (float*)d_ws;                       // [2][SQ][NG] = 64MB
  float* bufA = xp + (size_t)2 * SQ * NG;           // [SQ][512]   = 16MB
  float* bufB = bufA + (size_t)SQ * 512;            // [SQ][512]   = 16MB

  const dim3 ggrid(SQ / 64, 32);

  // layer 0
  gemm_xp<<<ggrid, 256, 0, stream>>>(x, 1024, w_ih0, b0, xp);
  lstm_rec<<<2, 1024, 0, stream>>>(w_hh0, xp, bufA);

  // layers 1..4
  float* cur = bufA;
  float* nxt = bufB;
  for (int l = 0; l < 4; ++l) {
    gemm_xp<<<ggrid, 256, 0, stream>>>(cur, 512, w_ih + (size_t)l * 2 * 512 * 1024,
                                       b + (size_t)l * 2 * 1024, xp);
    lstm_rec<<<2, 1024, 0, stream>>>(w_hh + (size_t)l * 2 * 256 * 1024, xp, nxt);
    float* tmp = cur; cur = nxt; nxt = tmp;
  }

  // head (cur == bufA after 4 swaps)
  cls_k<<<1, 512, 0, stream>>>(cur, w1, b1, w2, b2, (float*)d_out);
}